// Round 3
// baseline (332.403 us; speedup 1.0000x reference)
//
#include <hip/hip_runtime.h>

// x (B=64, C=256, T=2048) fp32; conv_weight (256,256,3); beta (1,); b (256,).
// Output spikes (B,C,T) fp32 in {0,1}. 16384 serial-in-T row recurrences.
// Parallelism cap = 256 waves; bottleneck is the dependent ALU chain of the
// recurrence (round 2: 134 cyc/step, VALUBusy 5%). Fix: 2 rows per thread ->
// two interleaved independent chains per lane (issue covers latency).
#define C_DIM 256
#define T_DIM 2048
#define B_DIM 64
#define NROWS (B_DIM * C_DIM)  // 16384
#define RPB   128              // rows per block (2 per thread)
#define PAIRS 64               // row pairs per block = wave size
#define TW    128              // timesteps per tile (512 B per row)
#define NT    (T_DIM / TW)     // 16 tiles
#define GSTR  260              // floats per pair group: 256 data + 4 pad (16B-aligned,
                               // stride 1040B: proven 0 LDS conflicts in round 2)

__device__ __forceinline__ float sqrn(float v) { return __fmul_rn(v, v); }

// norm[c] = sum of squares of 768 floats in numpy's exact pairwise order
// (768->384->192->96; 96-blocks via 8-accumulator unrolled loop).
// Verified bit-exact (rounds 1-2 absmax 0). DO NOT change the summation tree.
__global__ __launch_bounds__(64) void norm_kernel(const float* __restrict__ w,
                                                  const float* __restrict__ b,
                                                  float* __restrict__ bn,
                                                  float* __restrict__ ninv) {
    const int c = blockIdx.x;
    const int k = threadIdx.x;
    __shared__ float q[8];
    if (k < 8) {
        const float* a = w + c * 768 + k * 96;
        float r0 = sqrn(a[0]), r1 = sqrn(a[1]), r2 = sqrn(a[2]), r3 = sqrn(a[3]);
        float r4 = sqrn(a[4]), r5 = sqrn(a[5]), r6 = sqrn(a[6]), r7 = sqrn(a[7]);
        #pragma unroll
        for (int i = 8; i < 96; i += 8) {
            r0 = __fadd_rn(r0, sqrn(a[i + 0]));
            r1 = __fadd_rn(r1, sqrn(a[i + 1]));
            r2 = __fadd_rn(r2, sqrn(a[i + 2]));
            r3 = __fadd_rn(r3, sqrn(a[i + 3]));
            r4 = __fadd_rn(r4, sqrn(a[i + 4]));
            r5 = __fadd_rn(r5, sqrn(a[i + 5]));
            r6 = __fadd_rn(r6, sqrn(a[i + 6]));
            r7 = __fadd_rn(r7, sqrn(a[i + 7]));
        }
        q[k] = __fadd_rn(__fadd_rn(__fadd_rn(r0, r1), __fadd_rn(r2, r3)),
                         __fadd_rn(__fadd_rn(r4, r5), __fadd_rn(r6, r7)));
    }
    __syncthreads();
    if (k == 0) {
        float s = __fadd_rn(__fadd_rn(__fadd_rn(q[0], q[1]), __fadd_rn(q[2], q[3])),
                            __fadd_rn(__fadd_rn(q[4], q[5]), __fadd_rn(q[6], q[7])));
        bn[c]   = __fmul_rn(b[c], s);
        ninv[c] = 1.0f / __fadd_rn(s, 1e-8f);
    }
}

// Two interleaved LIF steps (rows A,B), numpy fp32 semantics per op.
// Chain shortening vs rounds 1-2 (both bit-exact):
//  - rst = spk?bn:0 replaces spk*bn (spk is exactly 0/1 -> identical value)
//  - spike = fl(mem*inv) > b replaces fl(fl(mem*inv)-b) > 0: IEEE subtraction
//    is sign-exact (fl(a-b)>0 <=> a>b; a-b subnormal requires both operands
//    subnormal, but b ~= 1), so the comparison is bit-identical.
__device__ __forceinline__ void step2(float xa, float xb_,
                                      float& memA, float& memB, bool& sA, bool& sB,
                                      float& oa, float& ob_,
                                      float bnA, float bnB, float beta, float omb,
                                      float niA, float niB, float bcA, float bcB) {
    float rA = sA ? bnA : 0.0f;
    float rB = sB ? bnB : 0.0f;
    memA = __fadd_rn(__fmul_rn(__fsub_rn(memA, rA), beta), __fmul_rn(xa,  omb));
    memB = __fadd_rn(__fmul_rn(__fsub_rn(memB, rB), beta), __fmul_rn(xb_, omb));
    sA = __fmul_rn(memA, niA) > bcA;
    sB = __fmul_rn(memB, niB) > bcB;
    oa  = sA ? 1.0f : 0.0f;
    ob_ = sB ? 1.0f : 0.0f;
}

// s_waitcnt immediates (gfx9: vm[3:0]|exp[6:4]|lgkm[11:8]|vm[5:4]@[15:14])
#define WAITCNT_VM0    0x0F70  // vmcnt(0),  lgkm no-wait
#define WAITCNT_VM62   0xCF7E  // vmcnt(62), lgkm no-wait
#define WAITCNT_LGKM0  0xC07F  // lgkmcnt(0), vm no-wait

#define LDS_PTR(p) ((__attribute__((address_space(3))) void*)(p))
#define GLB_PTR(p) ((const __attribute__((address_space(1))) void*)(p))

// Block = 1 wave = 64 threads, 128 rows (thread j owns rows 2j, 2j+1).
// Per tile (128 rows x 128 t):
//   fill : 64x global_load_lds_dwordx4; instr r = pair r's two 512B chunks
//          (lanes 0-31 -> row 2r, lanes 32-63 -> row 2r+1), contiguous 1KB LDS
//   comp : thread j walks its pair group via b128, two interleaved chains,
//          spikes written back IN-PLACE
//   drain: instr r = pair r -> lane l reads float4 l -> coalesced 1KB store
// Double-buffered: 2 x 64 x 260 floats = 130 KB LDS. Single wave per block ->
// no __syncthreads (would drain vmcnt and kill the DMA prefetch).
__global__ __launch_bounds__(64, 1) void lif_kernel(const float* __restrict__ x,
                                                    const float* __restrict__ beta_p,
                                                    const float* __restrict__ b,
                                                    const float* __restrict__ bn,
                                                    const float* __restrict__ ninv,
                                                    float* __restrict__ out) {
    __shared__ __align__(16) float lds[2][PAIRS * GSTR];

    const int lane = threadIdx.x;          // 0..63
    const int row0 = blockIdx.x * RPB;     // 128 rows per block
    const int rowA = row0 + 2 * lane;
    const int cA = rowA & (C_DIM - 1);
    const int cB = (rowA + 1) & (C_DIM - 1);

    const float beta = beta_p[0];
    const float omb  = __fsub_rn(1.0f, beta);
    const float bnA = bn[cA], bnB = bn[cB];
    const float niA = ninv[cA], niB = ninv[cB];
    const float bcA = b[cA],   bcB = b[cB];

    // Per-lane global offset for DMA fill / drain store:
    // lane<32 -> row 2r, granule lane; lane>=32 -> row 2r+1, granule lane-32.
    const size_t lrow = (size_t)(lane >> 5) * T_DIM + (size_t)(lane & 31) * 4;
    const float* xb = x   + (size_t)row0 * T_DIM + lrow;
    float*       ob = out + (size_t)row0 * T_DIM + lrow;

    // Prefetch tile 0 into buffer 0.
    #pragma unroll
    for (int r = 0; r < PAIRS; ++r)
        __builtin_amdgcn_global_load_lds(GLB_PTR(xb + (size_t)(2 * r) * T_DIM),
                                         LDS_PTR(&lds[0][r * GSTR]), 16, 0, 0);

    float memA = 0.0f, memB = 0.0f;
    bool  sA = false, sB = false;

    #pragma unroll 1
    for (int k = 0; k < NT; ++k) {
        // vmcnt retires in order; at k>0 the newest 64 outstanding ops are the
        // prior tile's drain stores, so vmcnt(62) proves this tile's 64 DMA
        // loads landed without stalling on store retirement.
        if (k == 0) __builtin_amdgcn_s_waitcnt(WAITCNT_VM0);
        else        __builtin_amdgcn_s_waitcnt(WAITCNT_VM62);

        // Kick next tile's DMA into the other buffer.
        if (k + 1 < NT) {
            const float* xt = xb + (size_t)(k + 1) * TW;
            #pragma unroll
            for (int r = 0; r < PAIRS; ++r)
                __builtin_amdgcn_global_load_lds(GLB_PTR(xt + (size_t)(2 * r) * T_DIM),
                                                 LDS_PTR(&lds[(k + 1) & 1][r * GSTR]),
                                                 16, 0, 0);
        }

        // Compute tile k: two interleaved chains per thread, in-place writeback.
        float* buf = &lds[k & 1][0];
        float* mA  = buf + lane * GSTR;   // row 2*lane chunk (128 floats)
        float* mB  = mA + TW;             // row 2*lane+1 chunk
        #pragma unroll 4
        for (int g = 0; g < TW / 4; ++g) {
            float4 va = *(const float4*)(mA + 4 * g);
            float4 vb = *(const float4*)(mB + 4 * g);
            float4 oa, obv;
            step2(va.x, vb.x, memA, memB, sA, sB, oa.x, obv.x, bnA, bnB, beta, omb, niA, niB, bcA, bcB);
            step2(va.y, vb.y, memA, memB, sA, sB, oa.y, obv.y, bnA, bnB, beta, omb, niA, niB, bcA, bcB);
            step2(va.z, vb.z, memA, memB, sA, sB, oa.z, obv.z, bnA, bnB, beta, omb, niA, niB, bcA, bcB);
            step2(va.w, vb.w, memA, memB, sA, sB, oa.w, obv.w, bnA, bnB, beta, omb, niA, niB, bcA, bcB);
            *(float4*)(mA + 4 * g) = oa;
            *(float4*)(mB + 4 * g) = obv;
        }

        // Cross-lane handoff (drain reads other lanes' rows): drain DS pipe.
        __builtin_amdgcn_s_waitcnt(WAITCNT_LGKM0);

        // Drain: instr r = pair r, lane l reads float4 l of the 1KB group ->
        // two contiguous 512B runs per store instruction (fully merged lines).
        float* ot = ob + (size_t)k * TW;
        #pragma unroll
        for (int r = 0; r < PAIRS; ++r) {
            float4 v = *(const float4*)(buf + r * GSTR + 4 * lane);
            *(float4*)(ot + (size_t)(2 * r) * T_DIM) = v;
        }
    }
}

extern "C" void kernel_launch(void* const* d_in, const int* in_sizes, int n_in,
                              void* d_out, int out_size, void* d_ws, size_t ws_size,
                              hipStream_t stream) {
    const float* x    = (const float*)d_in[0];
    const float* w    = (const float*)d_in[1];
    const float* beta = (const float*)d_in[2];
    const float* b    = (const float*)d_in[3];
    float* out  = (float*)d_out;
    float* bn   = (float*)d_ws;          // 256 floats
    float* ninv = bn + C_DIM;            // 256 floats

    norm_kernel<<<C_DIM, 64, 0, stream>>>(w, b, bn, ninv);
    lif_kernel<<<NROWS / RPB, 64, 0, stream>>>(x, beta, b, bn, ninv, out);
}

// Round 4
// 280.340 us; speedup vs baseline: 1.1857x; 1.1857x over previous
//
#include <hip/hip_runtime.h>

// x (B=64, C=256, T=2048) fp32; conv_weight (256,256,3); beta (1,); b (256,).
// Output spikes (B,C,T) fp32 in {0,1}. 16384 serial-in-T row recurrences.
// Parallelism is pinned: 16384 rows = 256 blocks x 64 threads, 1 row/thread,
// 1 wave/CU (round 3 proved fewer/fatter blocks lose half the chip).
// Bottleneck is the dependent chain of the recurrence. Round 4: restructure to
// a 4-op hazard-free chain (speculative dual-path update + sign-bit select,
// no v_cmp/v_cndmask/VCC in the loop).
#define C_DIM 256
#define T_DIM 2048
#define B_DIM 64
#define NROWS (B_DIM * C_DIM)
#define RPB 64                 // rows per block (= wave size)
#define TW 256                 // tile width in floats (1 KB per row per tile)
#define NT (T_DIM / TW)        // 8 tiles
#define RSTRIDE 260            // LDS row stride (floats): odd granule count -> 0 conflicts (proven r2)

__device__ __forceinline__ float sqrn(float v) { return __fmul_rn(v, v); }

// norm[c] = sum of squares of 768 floats in numpy's exact pairwise order
// (768->384->192->96; 96-blocks via 8-accumulator unrolled loop).
// Verified bit-exact (rounds 1-3 absmax 0). DO NOT change the summation tree.
__global__ __launch_bounds__(64) void norm_kernel(const float* __restrict__ w,
                                                  const float* __restrict__ b,
                                                  float* __restrict__ bn,
                                                  float* __restrict__ ninv) {
    const int c = blockIdx.x;
    const int k = threadIdx.x;
    __shared__ float q[8];
    if (k < 8) {
        const float* a = w + c * 768 + k * 96;
        float r0 = sqrn(a[0]), r1 = sqrn(a[1]), r2 = sqrn(a[2]), r3 = sqrn(a[3]);
        float r4 = sqrn(a[4]), r5 = sqrn(a[5]), r6 = sqrn(a[6]), r7 = sqrn(a[7]);
        #pragma unroll
        for (int i = 8; i < 96; i += 8) {
            r0 = __fadd_rn(r0, sqrn(a[i + 0]));
            r1 = __fadd_rn(r1, sqrn(a[i + 1]));
            r2 = __fadd_rn(r2, sqrn(a[i + 2]));
            r3 = __fadd_rn(r3, sqrn(a[i + 3]));
            r4 = __fadd_rn(r4, sqrn(a[i + 4]));
            r5 = __fadd_rn(r5, sqrn(a[i + 5]));
            r6 = __fadd_rn(r6, sqrn(a[i + 6]));
            r7 = __fadd_rn(r7, sqrn(a[i + 7]));
        }
        q[k] = __fadd_rn(__fadd_rn(__fadd_rn(r0, r1), __fadd_rn(r2, r3)),
                         __fadd_rn(__fadd_rn(r4, r5), __fadd_rn(r6, r7)));
    }
    __syncthreads();
    if (k == 0) {
        float s = __fadd_rn(__fadd_rn(__fadd_rn(q[0], q[1]), __fadd_rn(q[2], q[3])),
                            __fadd_rn(__fadd_rn(q[4], q[5]), __fadd_rn(q[6], q[7])));
        bn[c]   = __fmul_rn(b[c], s);
        ninv[c] = 1.0f / __fadd_rn(s, 1e-8f);
    }
}

// One LIF step, 4-op critical chain, bit-exact vs numpy semantics:
//  - both reset paths computed speculatively off mem:
//      m0 = fl(fl(mem*beta)+xw)            (no spike; mem-0 == mem incl -0)
//      m1 = fl(fl(fl(mem-bn)*beta)+xw)     (spike; rst = 1.0*bn == bn exactly)
//  - select via bit-blend (v_bfi), mask from previous step's sign bit
//  - spike predicate: fl(mem*ni) > bc  <=>  signbit(fl(bc - p)) == 1
//      (IEEE sub is sign-exact for distinct operands; equality -> +0 -> no
//       spike, matching strict >; chain-equivalent form verified absmax 0 in r3)
//  - no v_cmp / v_cndmask / VCC anywhere -> no SGPR-hazard wait states
__device__ __forceinline__ float step_fast(float xw, float& mem, int& mask,
                                           float bnc, float beta, float nic, float bc) {
    float m0 = __fmul_rn(mem, beta);
    float m1 = __fmul_rn(__fsub_rn(mem, bnc), beta);
    m0 = __fadd_rn(m0, xw);
    m1 = __fadd_rn(m1, xw);
    int mi = (__float_as_int(m1) & mask) | (__float_as_int(m0) & ~mask);
    mem = __int_as_float(mi);
    float p = __fmul_rn(mem, nic);
    float d = __fsub_rn(bc, p);
    mask = __float_as_int(d) >> 31;                 // -1 if spike else 0
    return __int_as_float(mask & 0x3f800000);       // 1.0f or 0.0f
}

// s_waitcnt immediates (gfx9 encoding: vm[3:0]|exp[6:4]|lgkm[11:8]|vm[5:4]@[15:14])
#define WAITCNT_VM0    0x0F70  // vmcnt(0),  lgkm no-wait
#define WAITCNT_VM62   0xCF7E  // vmcnt(62), lgkm no-wait
#define WAITCNT_LGKM0  0xC07F  // lgkmcnt(0), vm no-wait

#define LDS_PTR(p) ((__attribute__((address_space(3))) void*)(p))
#define GLB_PTR(p) ((const __attribute__((address_space(1))) void*)(p))

// Block = 1 wave = 64 rows (thread j owns row j). Per tile (64 rows x 256 t):
//   fill : 64x global_load_lds_dwordx4 — each instr = one row's 1 KB, coalesced
//   comp : thread j walks its row in LDS via b128, writes spikes back IN-PLACE
//   drain: lane i reads row r's granule i (b128) -> coalesced 1 KB float4 store
// Double-buffered input tiles, in-place output staging: 133 KB LDS.
// Single wave per block -> no __syncthreads (would drain vmcnt / kill prefetch).
// This shell measured exactly 1.00x write amplification, 0 LDS conflicts (r2).
__global__ __launch_bounds__(64, 1) void lif_kernel(const float* __restrict__ x,
                                                    const float* __restrict__ beta_p,
                                                    const float* __restrict__ b,
                                                    const float* __restrict__ bn,
                                                    const float* __restrict__ ninv,
                                                    float* __restrict__ out) {
    __shared__ __align__(16) float lds[2][RPB * RSTRIDE];

    const int lane = threadIdx.x;           // 0..63
    const int row0 = blockIdx.x * RPB;      // 64 rows per block
    const int c    = (row0 + lane) & (C_DIM - 1);

    const float beta = beta_p[0];
    const float omb  = __fsub_rn(1.0f, beta);
    const float bnc  = bn[c];
    const float nic  = ninv[c];
    const float bc   = b[c];

    const float* xbase = x + (size_t)row0 * T_DIM + lane * 4;
    float*       obase = out + (size_t)row0 * T_DIM + lane * 4;

    // Prefetch tile 0 into buffer 0.
    #pragma unroll
    for (int r = 0; r < RPB; ++r) {
        __builtin_amdgcn_global_load_lds(GLB_PTR(xbase + (size_t)r * T_DIM),
                                         LDS_PTR(&lds[0][r * RSTRIDE]), 16, 0, 0);
    }

    float mem = 0.0f;
    int   mask = 0;        // -1 after a spike, 0 otherwise

    #pragma unroll 1
    for (int k = 0; k < NT; ++k) {
        // vmcnt retires in order; at k>0 the 63 newest outstanding ops are
        // prior-tile stores, so vmcnt(62) proves all 64 DMA loads of tile k
        // landed without stalling on store retirement.
        if (k == 0) __builtin_amdgcn_s_waitcnt(WAITCNT_VM0);
        else        __builtin_amdgcn_s_waitcnt(WAITCNT_VM62);

        // Kick off next tile's DMA (issued after the wait so it isn't drained).
        if (k + 1 < NT) {
            const float* xt = xbase + (size_t)(k + 1) * TW;
            #pragma unroll
            for (int r = 0; r < RPB; ++r) {
                __builtin_amdgcn_global_load_lds(GLB_PTR(xt + (size_t)r * T_DIM),
                                                 LDS_PTR(&lds[(k + 1) & 1][r * RSTRIDE]),
                                                 16, 0, 0);
            }
        }

        // Compute tile k in-place. xw = fl(x*(1-beta)) hoisted off the chain.
        float* buf = &lds[k & 1][0];
        float* myrow = buf + lane * RSTRIDE;
        #pragma unroll 4
        for (int g = 0; g < TW / 4; ++g) {
            float4 v = *(const float4*)(myrow + 4 * g);
            float xw0 = __fmul_rn(v.x, omb);
            float xw1 = __fmul_rn(v.y, omb);
            float xw2 = __fmul_rn(v.z, omb);
            float xw3 = __fmul_rn(v.w, omb);
            float4 o;
            o.x = step_fast(xw0, mem, mask, bnc, beta, nic, bc);
            o.y = step_fast(xw1, mem, mask, bnc, beta, nic, bc);
            o.z = step_fast(xw2, mem, mask, bnc, beta, nic, bc);
            o.w = step_fast(xw3, mem, mask, bnc, beta, nic, bc);
            *(float4*)(myrow + 4 * g) = o;
        }

        // Cross-lane handoff before drain reads other lanes' rows.
        __builtin_amdgcn_s_waitcnt(WAITCNT_LGKM0);

        // Drain: coalesced 1 KB stores, one row per instruction.
        float* ot = obase + (size_t)k * TW;
        #pragma unroll
        for (int r = 0; r < RPB; ++r) {
            float4 v = *(const float4*)(buf + r * RSTRIDE + 4 * lane);
            *(float4*)(ot + (size_t)r * T_DIM) = v;
        }
    }
}

extern "C" void kernel_launch(void* const* d_in, const int* in_sizes, int n_in,
                              void* d_out, int out_size, void* d_ws, size_t ws_size,
                              hipStream_t stream) {
    const float* x    = (const float*)d_in[0];
    const float* w    = (const float*)d_in[1];
    const float* beta = (const float*)d_in[2];
    const float* b    = (const float*)d_in[3];
    float* out  = (float*)d_out;
    float* bn   = (float*)d_ws;          // 256 floats
    float* ninv = bn + C_DIM;            // 256 floats

    norm_kernel<<<C_DIM, 64, 0, stream>>>(w, b, bn, ninv);
    lif_kernel<<<NROWS / RPB, 64, 0, stream>>>(x, beta, b, bn, ninv, out);
}